// Round 4
// baseline (1230.715 us; speedup 1.0000x reference)
//
#include <hip/hip_runtime.h>
#include <stdint.h>

#define N_    8192
#define DIN   1024
#define DMID  256
#define DEMB  64

typedef __bf16 bf16x8 __attribute__((ext_vector_type(8)));
typedef float  f32x4  __attribute__((ext_vector_type(4)));

#define MFMA16(a, b, c) __builtin_amdgcn_mfma_f32_16x16x32_bf16((a), (b), (c), 0, 0, 0)

static __device__ __forceinline__ unsigned short f2bfu(float f) {
    union { float f; unsigned int u; } v; v.f = f;
    unsigned int r = v.u + 0x7FFFu + ((v.u >> 16) & 1u);
    return (unsigned short)(r >> 16);
}

// ---------------------------------------------------------------------------
// Tiny setup: W1 [1024][256] -> W1T bf16 [256][1024]; W2 [256][64] -> W2T [64][256]
// ---------------------------------------------------------------------------
__global__ void k_setup(const float* __restrict__ W1, const float* __restrict__ W2,
                        unsigned short* __restrict__ W1T, unsigned short* __restrict__ W2T) {
    int idx = blockIdx.x * 256 + threadIdx.x;
    if (idx < DIN * DMID) {
        int k = idx / DMID, c = idx % DMID;
        W1T[c * DIN + k] = f2bfu(W1[idx]);
    }
    int i2 = idx - DIN * DMID;
    if (i2 >= 0 && i2 < DMID * DEMB) {
        int k = i2 / DEMB, c = i2 % DEMB;
        W2T[c * DMID + k] = f2bfu(W2[i2]);
    }
}

// ---------------------------------------------------------------------------
// Generic skinny GEMM: C[M x BN] = A[M x K] * B^T-storage, BM=32 rows/block.
//   A: row-major, fp32 (AF32=1, converted on the fly) or bf16 (AF32=0)
//   Bg: "transposed" bf16 storage [BN][K] so k is contiguous per output col.
//   OUTMODE 0: write bf16 transposed  Og[col*N_ + row]
//   OUTMODE 1: write bf16 row-major   Og[row*BN + col]   (RELU optional)
//   OUTMODE 2: like 1, plus sq[row] = sum_col bf16(val)^2  (G4: emb + sq)
// 512 threads = 8 waves; wave: row-tile = w&1, col-group = w>>1 (NCT tiles).
// A (fp32, stream-once per block) is loaded nontemporal: keeps the reused
// B-panel (AT = 4 MB ~= one XCD L2) from being thrashed by the L stream.
// ---------------------------------------------------------------------------
template<int BN, int AF32, int OUTMODE, int RELU>
__global__ __launch_bounds__(512, 2)
void k_gemm(const void* __restrict__ Ag_, const unsigned short* __restrict__ Bg,
            void* __restrict__ Og, float* __restrict__ sqg,
            int K, int lda, int ldb)
{
    constexpr int NCT = BN / 64;   // col-tiles per wave (4 for BN=256, 1 for BN=64)
    const int tid  = threadIdx.x;
    const int w    = tid >> 6;
    const int lane = tid & 63;
    const int l16  = lane & 15, lhi = lane >> 4;
    const int row0 = blockIdx.x * 32;

    __shared__ __align__(16) unsigned short At[2][32 * 32];
    __shared__ __align__(16) unsigned short Bt[2][BN * 32];
    __shared__ float sql[32];

    if (OUTMODE == 2 && tid < 32) sql[tid] = 0.0f;

    const float*          Af = (const float*)Ag_;
    const unsigned short* Ah = (const unsigned short*)Ag_;

    // A staging: thread -> (row, 2 elems): row = tid>>4 (0..31), k2 = (tid&15)*2
    const int s_arow = tid >> 4;
    const int s_ak   = (tid & 15) * 2;

    f32x4 acc[NCT];
    #pragma unroll
    for (int i = 0; i < NCT; ++i) { f32x4 z = {0.f, 0.f, 0.f, 0.f}; acc[i] = z; }

    float2  arf; ushort2 arh; uint4 brg[2];
    const int NT = K >> 5;

    auto stage_load = [&](int t) {
        int k0 = t << 5;
        if (AF32) {
            // stream-once data: nontemporal 8B load (global_load_dwordx2 ... nt)
            union { double d; float2 f; } cvt;
            cvt.d = __builtin_nontemporal_load(
                (const double*)&Af[(size_t)(row0 + s_arow) * lda + k0 + s_ak]);
            arf = cvt.f;
        } else {
            arh = *(const ushort2*)&Ah[(size_t)(row0 + s_arow) * lda + k0 + s_ak];
        }
        if (BN == 256) {
            #pragma unroll
            for (int i = 0; i < 2; ++i) {
                int u = tid + i * 512;
                int col = u >> 2, ks = (u & 3) * 8;
                brg[i] = *(const uint4*)&Bg[(size_t)col * ldb + k0 + ks];
            }
        } else {
            if (tid < 256) {
                int col = tid >> 2, ks = (tid & 3) * 8;
                brg[0] = *(const uint4*)&Bg[(size_t)col * ldb + k0 + ks];
            }
        }
    };
    auto stage_write = [&](int buf) {
        {
            ushort2 o;
            if (AF32) { o.x = f2bfu(arf.x); o.y = f2bfu(arf.y); }
            else      { o = arh; }
            int e = (s_arow * 32 + s_ak) ^ ((s_arow & 7) << 3);
            *(ushort2*)&At[buf][e] = o;
        }
        if (BN == 256) {
            #pragma unroll
            for (int i = 0; i < 2; ++i) {
                int u = tid + i * 512;
                int col = u >> 2, ks = (u & 3) * 8;
                int e = (col * 32 + ks) ^ ((col & 7) << 3);
                *(uint4*)&Bt[buf][e] = brg[i];
            }
        } else {
            if (tid < 256) {
                int col = tid >> 2, ks = (tid & 3) * 8;
                int e = (col * 32 + ks) ^ ((col & 7) << 3);
                *(uint4*)&Bt[buf][e] = brg[0];
            }
        }
    };

    stage_load(0);
    stage_write(0);
    __syncthreads();

    const int a_r   = 16 * (w & 1) + l16;
    const int a_off = (a_r * 32 + lhi * 8) ^ ((a_r & 7) << 3);

    for (int t = 0; t < NT; ++t) {
        int cur = t & 1;
        if (t + 1 < NT) stage_load(t + 1);        // issue next-tile global loads early
        bf16x8 a = *(const bf16x8*)&At[cur][a_off];
        #pragma unroll
        for (int ct = 0; ct < NCT; ++ct) {
            int col = ((w >> 1) * NCT + ct) * 16 + l16;
            int e = (col * 32 + lhi * 8) ^ ((col & 7) << 3);
            bf16x8 b = *(const bf16x8*)&Bt[cur][e];
            acc[ct] = MFMA16(a, b, acc[ct]);
        }
        __syncthreads();
        if (t + 1 < NT) {
            stage_write(cur ^ 1);
            __syncthreads();
        }
    }

    // ---- epilogue ----
    if (OUTMODE == 0) {
        unsigned short* OT = (unsigned short*)Og;
        int rowb = row0 + 16 * (w & 1) + lhi * 4;
        #pragma unroll
        for (int ct = 0; ct < NCT; ++ct) {
            int col = ((w >> 1) * NCT + ct) * 16 + l16;
            ushort4 o;
            o.x = f2bfu(acc[ct][0]); o.y = f2bfu(acc[ct][1]);
            o.z = f2bfu(acc[ct][2]); o.w = f2bfu(acc[ct][3]);
            *(ushort4*)&OT[(size_t)col * N_ + rowb] = o;
        }
    } else {
        unsigned short* O = (unsigned short*)Og;
        float sp[4] = {0.f, 0.f, 0.f, 0.f};
        #pragma unroll
        for (int ct = 0; ct < NCT; ++ct) {
            int col = ((w >> 1) * NCT + ct) * 16 + l16;
            #pragma unroll
            for (int i = 0; i < 4; ++i) {
                int row = row0 + 16 * (w & 1) + lhi * 4 + i;
                float v = acc[ct][i];
                if (RELU) v = fmaxf(v, 0.f);
                unsigned short u = f2bfu(v);
                O[(size_t)row * BN + col] = u;
                if (OUTMODE == 2) {
                    union { unsigned int ui; float f; } cv; cv.ui = (unsigned int)u << 16;
                    sp[i] += cv.f * cv.f;   // square the ROUNDED value: keeps dist_ii ~ 0
                }
            }
        }
        if (OUTMODE == 2) {
            #pragma unroll
            for (int off = 1; off < 16; off <<= 1) {
                #pragma unroll
                for (int i = 0; i < 4; ++i) sp[i] += __shfl_xor(sp[i], off);
            }
            if (l16 == 0) {
                #pragma unroll
                for (int i = 0; i < 4; ++i)
                    atomicAdd(&sql[16 * (w & 1) + lhi * 4 + i], sp[i]);
            }
            __syncthreads();
            if (tid < 32) sqg[row0 + tid] = sql[tid];
        }
    }
    (void)sqg;
}

// ---------------------------------------------------------------------------
// Fused pairwise-dist + row softmax, TWO passes (sum, then write).
// NO max subtraction needed: dist >= 0 and dist_ii ~= 0 (sq uses the rounded
// bf16 emb), so row-max of z = -dist is ~0. exp(-d) <= 1 (no overflow) and
// the diagonal term keeps sum >= ~1 (no div-by-0). Softmax shift-invariance
// makes this mathematically identical to the reference's max-subtracted form.
// Block: 32 rows (2 row-tiles), 512 thr = 8 waves; wave w owns cols [w*1024, +1024).
// Each pass recomputes G = emb@emb^T tiles via MFMA (emb is 1 MB bf16,
// L2-resident).
// ---------------------------------------------------------------------------
__global__ __launch_bounds__(512, 2)
void k_softmax(const unsigned short* __restrict__ embb, const float* __restrict__ sq,
               float* __restrict__ out)
{
    const int tid  = threadIdx.x;
    const int w    = tid >> 6;
    const int lane = tid & 63;
    const int l16  = lane & 15, lhi = lane >> 4;
    const int row0 = blockIdx.x * 32;

    __shared__ float red_s[8][32];
    __shared__ float srow[32];

    bf16x8 afr[2][2];
    #pragma unroll
    for (int tr = 0; tr < 2; ++tr)
        #pragma unroll
        for (int ks = 0; ks < 2; ++ks)
            afr[tr][ks] = *(const bf16x8*)&embb[(size_t)(row0 + 16 * tr + l16) * 64 + ks * 32 + lhi * 8];

    float sqr[2][4];
    #pragma unroll
    for (int tr = 0; tr < 2; ++tr)
        #pragma unroll
        for (int i = 0; i < 4; ++i)
            sqr[tr][i] = sq[row0 + 16 * tr + lhi * 4 + i];

    const int colw0 = w * 1024;

    // ---- pass A: row sum of exp(-d) over this wave's 1024 cols ----
    float s_[2][4] = {{0.f,0.f,0.f,0.f},{0.f,0.f,0.f,0.f}};

    for (int ch = 0; ch < 16; ++ch) {
        int cb = colw0 + ch * 64;
        #pragma unroll
        for (int ct = 0; ct < 4; ++ct) {
            int col = cb + ct * 16 + l16;
            bf16x8 b0 = *(const bf16x8*)&embb[(size_t)col * 64 + lhi * 8];
            bf16x8 b1 = *(const bf16x8*)&embb[(size_t)col * 64 + 32 + lhi * 8];
            float sqc = sq[col];
            #pragma unroll
            for (int tr = 0; tr < 2; ++tr) {
                f32x4 g = {0.f, 0.f, 0.f, 0.f};
                g = MFMA16(afr[tr][0], b0, g);
                g = MFMA16(afr[tr][1], b1, g);
                #pragma unroll
                for (int i = 0; i < 4; ++i) {
                    // nd = -dist = min(2g - (sqr+sqc), 0) ; exp(nd) <= 1
                    float nd = fminf(__builtin_fmaf(2.0f, g[i], -(sqr[tr][i] + sqc)), 0.0f);
                    s_[tr][i] += __expf(nd);
                }
            }
        }
    }

    // plain sum-reduce over the 16 column-lanes (l16)
    #pragma unroll
    for (int off = 1; off < 16; off <<= 1) {
        #pragma unroll
        for (int tr = 0; tr < 2; ++tr)
            #pragma unroll
            for (int i = 0; i < 4; ++i)
                s_[tr][i] += __shfl_xor(s_[tr][i], off);
    }
    if (l16 == 0) {
        #pragma unroll
        for (int tr = 0; tr < 2; ++tr)
            #pragma unroll
            for (int i = 0; i < 4; ++i)
                red_s[w][16 * tr + lhi * 4 + i] = s_[tr][i];
    }
    __syncthreads();
    if (tid < 32) {
        float s = red_s[0][tid];
        #pragma unroll
        for (int j = 1; j < 8; ++j) s += red_s[j][tid];
        srow[tid] = 1.0f / s;   // s >= exp(-dist_ii) ~= 1 — safe
    }
    __syncthreads();
    float rsloc[2][4];
    #pragma unroll
    for (int tr = 0; tr < 2; ++tr)
        #pragma unroll
        for (int i = 0; i < 4; ++i)
            rsloc[tr][i] = srow[16 * tr + lhi * 4 + i];

    // ---- pass B: recompute, normalize, write (nontemporal: keep emb in L2) ----
    for (int ch = 0; ch < 16; ++ch) {
        int cb = colw0 + ch * 64;
        #pragma unroll
        for (int ct = 0; ct < 4; ++ct) {
            int col = cb + ct * 16 + l16;
            bf16x8 b0 = *(const bf16x8*)&embb[(size_t)col * 64 + lhi * 8];
            bf16x8 b1 = *(const bf16x8*)&embb[(size_t)col * 64 + 32 + lhi * 8];
            float sqc = sq[col];
            #pragma unroll
            for (int tr = 0; tr < 2; ++tr) {
                f32x4 g = {0.f, 0.f, 0.f, 0.f};
                g = MFMA16(afr[tr][0], b0, g);
                g = MFMA16(afr[tr][1], b1, g);
                #pragma unroll
                for (int i = 0; i < 4; ++i) {
                    float nd = fminf(__builtin_fmaf(2.0f, g[i], -(sqr[tr][i] + sqc)), 0.0f);
                    float p = __expf(nd) * rsloc[tr][i] + 1e-10f;
                    int row = row0 + 16 * tr + lhi * 4 + i;
                    __builtin_nontemporal_store(p, &out[(size_t)row * N_ + col]);
                }
            }
        }
    }
}

// ---------------------------------------------------------------------------
// Workspace layout (needs ~12 MB):
//  [0,4M)    AT  bf16 [256][8192]   (X@W1)^T
//  [4M,8M)   h   bf16 [8192][256]
//  [8M,9M)   PT  bf16 [64][8192]    (h@W2)^T
//  [9M,10M)  EB  bf16 [8192][64]    emb
//  [10M,..)  SQ  f32  [8192]
//  [11M,..)  W1T bf16 [256][1024]
//  [11M+512K,..) W2T bf16 [64][256]
// ---------------------------------------------------------------------------
extern "C" void kernel_launch(void* const* d_in, const int* in_sizes, int n_in,
                              void* d_out, int out_size, void* d_ws, size_t ws_size,
                              hipStream_t stream)
{
    const float* L  = (const float*)d_in[0];
    const float* X  = (const float*)d_in[1];
    const float* W1 = (const float*)d_in[2];
    const float* W2 = (const float*)d_in[3];
    float* out = (float*)d_out;
    char* ws = (char*)d_ws;

    unsigned short* AT  = (unsigned short*)(ws);
    unsigned short* Hh  = (unsigned short*)(ws + (4ll  << 20));
    unsigned short* PT  = (unsigned short*)(ws + (8ll  << 20));
    unsigned short* EB  = (unsigned short*)(ws + (9ll  << 20));
    float*          SQ  = (float*)         (ws + (10ll << 20));
    unsigned short* W1T = (unsigned short*)(ws + (11ll << 20));
    unsigned short* W2T = (unsigned short*)(ws + (11ll << 20) + (512ll << 10));

    k_setup<<<(DIN * DMID + DMID * DEMB + 255) / 256, 256, 0, stream>>>(W1, W2, W1T, W2T);

    // A^T = (X @ W1)^T           [256][8192]
    k_gemm<256, 1, 0, 0><<<256, 512, 0, stream>>>(X,  W1T, AT, nullptr, DIN,  DIN,  DIN);
    // h = relu(L @ A)            [8192][256]
    k_gemm<256, 1, 1, 1><<<256, 512, 0, stream>>>(L,  AT,  Hh, nullptr, N_,   N_,   N_);
    // P^T = (h @ W2)^T           [64][8192]
    k_gemm< 64, 0, 0, 0><<<256, 512, 0, stream>>>(Hh, W2T, PT, nullptr, DMID, DMID, DMID);
    // emb = L @ P, sq = rowsum(emb^2)   [8192][64], [8192]
    k_gemm< 64, 1, 2, 0><<<256, 512, 0, stream>>>(L,  PT,  EB, SQ,      N_,   N_,   N_);
    // dist + softmax + 1e-10  -> out [8192][8192]
    k_softmax<<<256, 512, 0, stream>>>(EB, SQ, out);
}

// Round 8
// 1119.842 us; speedup vs baseline: 1.0990x; 1.0990x over previous
//
#include <hip/hip_runtime.h>
#include <stdint.h>

#define N_    8192
#define DIN   1024
#define DMID  256
#define DEMB  64

typedef __bf16 bf16x8 __attribute__((ext_vector_type(8)));
typedef float  f32x4  __attribute__((ext_vector_type(4)));

#define MFMA16(a, b, c) __builtin_amdgcn_mfma_f32_16x16x32_bf16((a), (b), (c), 0, 0, 0)

static __device__ __forceinline__ unsigned short f2bfu(float f) {
    union { float f; unsigned int u; } v; v.f = f;
    unsigned int r = v.u + 0x7FFFu + ((v.u >> 16) & 1u);
    return (unsigned short)(r >> 16);
}

// ---------------------------------------------------------------------------
// Tiny setup: W1 [1024][256] -> W1T bf16 [256][1024]; W2 [256][64] -> W2T [64][256]
// ---------------------------------------------------------------------------
__global__ void k_setup(const float* __restrict__ W1, const float* __restrict__ W2,
                        unsigned short* __restrict__ W1T, unsigned short* __restrict__ W2T) {
    int idx = blockIdx.x * 256 + threadIdx.x;
    if (idx < DIN * DMID) {
        int k = idx / DMID, c = idx % DMID;
        W1T[c * DIN + k] = f2bfu(W1[idx]);
    }
    int i2 = idx - DIN * DMID;
    if (i2 >= 0 && i2 < DMID * DEMB) {
        int k = i2 / DEMB, c = i2 % DEMB;
        W2T[c * DMID + k] = f2bfu(W2[i2]);
    }
}

// ---------------------------------------------------------------------------
// Generic skinny GEMM: C[M x BN] = A[M x K] * B^T-storage, BM=32 rows/block.
// R4 counters: 405 us, MfmaUtil 3.4%, VALU 4.4%, HBM 5%, Occ 23.6% (1 blk/CU)
// -> latency-bound: stage_write waited a full exposed load latency each iter.
// R5 fix: depth-2 register prefetch (2 named sets, loop unrolled x2 so the
// sets alternate WITHOUT reg-copies; a copy would WAR-stall on the in-flight
// load). Load for tile t+3 is issued ~2 full iterations before its LDS write.
// ---------------------------------------------------------------------------
template<int BN, int AF32, int OUTMODE, int RELU>
__global__ __launch_bounds__(512, 2)
void k_gemm(const void* __restrict__ Ag_, const unsigned short* __restrict__ Bg,
            void* __restrict__ Og, float* __restrict__ sqg,
            int K, int lda, int ldb)
{
    constexpr int NCT = BN / 64;   // col-tiles per wave (4 for BN=256, 1 for BN=64)
    const int tid  = threadIdx.x;
    const int w    = tid >> 6;
    const int lane = tid & 63;
    const int l16  = lane & 15, lhi = lane >> 4;
    const int row0 = blockIdx.x * 32;

    __shared__ __align__(16) unsigned short At[2][32 * 32];
    __shared__ __align__(16) unsigned short Bt[2][BN * 32];
    __shared__ float sql[32];

    if (OUTMODE == 2 && tid < 32) sql[tid] = 0.0f;

    const float*          Af = (const float*)Ag_;
    const unsigned short* Ah = (const unsigned short*)Ag_;

    // A staging: thread -> (row, 2 elems): row = tid>>4 (0..31), k2 = (tid&15)*2
    const int s_arow = tid >> 4;
    const int s_ak   = (tid & 15) * 2;

    f32x4 acc[NCT];
    #pragma unroll
    for (int i = 0; i < NCT; ++i) { f32x4 z = {0.f, 0.f, 0.f, 0.f}; acc[i] = z; }

    const int NT = K >> 5;   // always even, >= 8 for all call sites

    struct SReg { float2 arf; ushort2 arh; uint4 brg[2]; };
    SReg sa, sb;

    auto ld = [&](SReg& r, int t) {
        int k0 = t << 5;
        if (AF32) {
            // stream-once data: nontemporal 8B load
            union { double d; float2 f; } cvt;
            cvt.d = __builtin_nontemporal_load(
                (const double*)&Af[(size_t)(row0 + s_arow) * lda + k0 + s_ak]);
            r.arf = cvt.f;
        } else {
            r.arh = *(const ushort2*)&Ah[(size_t)(row0 + s_arow) * lda + k0 + s_ak];
        }
        if (BN == 256) {
            #pragma unroll
            for (int i = 0; i < 2; ++i) {
                int u = tid + i * 512;
                int col = u >> 2, ks = (u & 3) * 8;
                r.brg[i] = *(const uint4*)&Bg[(size_t)col * ldb + k0 + ks];
            }
        } else {
            if (tid < 256) {
                int col = tid >> 2, ks = (tid & 3) * 8;
                r.brg[0] = *(const uint4*)&Bg[(size_t)col * ldb + k0 + ks];
            }
        }
    };
    auto st = [&](int buf, SReg& r) {
        {
            ushort2 o;
            if (AF32) { o.x = f2bfu(r.arf.x); o.y = f2bfu(r.arf.y); }
            else      { o = r.arh; }
            int e = (s_arow * 32 + s_ak) ^ ((s_arow & 7) << 3);
            *(ushort2*)&At[buf][e] = o;
        }
        if (BN == 256) {
            #pragma unroll
            for (int i = 0; i < 2; ++i) {
                int u = tid + i * 512;
                int col = u >> 2, ks = (u & 3) * 8;
                int e = (col * 32 + ks) ^ ((col & 7) << 3);
                *(uint4*)&Bt[buf][e] = r.brg[i];
            }
        } else {
            if (tid < 256) {
                int col = tid >> 2, ks = (tid & 3) * 8;
                int e = (col * 32 + ks) ^ ((col & 7) << 3);
                *(uint4*)&Bt[buf][e] = r.brg[0];
            }
        }
    };

    const int a_r   = 16 * (w & 1) + l16;
    const int a_off = (a_r * 32 + lhi * 8) ^ ((a_r & 7) << 3);

    auto mm = [&](int cur) {
        bf16x8 a = *(const bf16x8*)&At[cur][a_off];
        #pragma unroll
        for (int ct = 0; ct < NCT; ++ct) {
            int col = ((w >> 1) * NCT + ct) * 16 + l16;
            int e = (col * 32 + lhi * 8) ^ ((col & 7) << 3);
            bf16x8 b = *(const bf16x8*)&Bt[cur][e];
            acc[ct] = MFMA16(a, b, acc[ct]);
        }
    };

    // prologue: tile0 staged; sa=tile1, sb=tile2 in flight
    ld(sa, 0);
    st(0, sa);
    ld(sa, 1);
    ld(sb, 2);
    __syncthreads();

    for (int t = 0; t < NT; t += 2) {
        mm(0);                         // tile t      (buf 0)
        __syncthreads();
        st(1, sa);                     // tile t+1 -> buf 1 (loads ~2 iters old)
        if (t + 3 < NT) ld(sa, t + 3);
        __syncthreads();
        mm(1);                         // tile t+1    (buf 1)
        __syncthreads();
        if (t + 2 < NT) {
            st(0, sb);                 // tile t+2 -> buf 0
            if (t + 4 < NT) ld(sb, t + 4);
            __syncthreads();
        }
    }

    // ---- epilogue ----
    if (OUTMODE == 0) {
        unsigned short* OT = (unsigned short*)Og;
        int rowb = row0 + 16 * (w & 1) + lhi * 4;
        #pragma unroll
        for (int ct = 0; ct < NCT; ++ct) {
            int col = ((w >> 1) * NCT + ct) * 16 + l16;
            ushort4 o;
            o.x = f2bfu(acc[ct][0]); o.y = f2bfu(acc[ct][1]);
            o.z = f2bfu(acc[ct][2]); o.w = f2bfu(acc[ct][3]);
            *(ushort4*)&OT[(size_t)col * N_ + rowb] = o;
        }
    } else {
        unsigned short* O = (unsigned short*)Og;
        float sp[4] = {0.f, 0.f, 0.f, 0.f};
        #pragma unroll
        for (int ct = 0; ct < NCT; ++ct) {
            int col = ((w >> 1) * NCT + ct) * 16 + l16;
            #pragma unroll
            for (int i = 0; i < 4; ++i) {
                int row = row0 + 16 * (w & 1) + lhi * 4 + i;
                float v = acc[ct][i];
                if (RELU) v = fmaxf(v, 0.f);
                unsigned short u = f2bfu(v);
                O[(size_t)row * BN + col] = u;
                if (OUTMODE == 2) {
                    union { unsigned int ui; float f; } cv; cv.ui = (unsigned int)u << 16;
                    sp[i] += cv.f * cv.f;   // square the ROUNDED value: keeps dist_ii ~ 0
                }
            }
        }
        if (OUTMODE == 2) {
            #pragma unroll
            for (int off = 1; off < 16; off <<= 1) {
                #pragma unroll
                for (int i = 0; i < 4; ++i) sp[i] += __shfl_xor(sp[i], off);
            }
            if (l16 == 0) {
                #pragma unroll
                for (int i = 0; i < 4; ++i)
                    atomicAdd(&sql[16 * (w & 1) + lhi * 4 + i], sp[i]);
            }
            __syncthreads();
            if (tid < 32) sqg[row0 + tid] = sql[tid];
        }
    }
    (void)sqg;
}

// ---------------------------------------------------------------------------
// Fused pairwise-dist + row softmax, TWO passes (sum, then write).
// No max subtraction: dist >= 0, dist_ii ~= 0 (sq uses rounded bf16 emb) ->
// row max of -dist is ~0; exp(-d) <= 1, diagonal keeps sum >= ~1.
// R5: 512 blocks x 16 rows (2 blocks/CU, was 1) + unroll-2 double-set reg
// prefetch of (b0,b1,sqc) so each wave keeps ~6 L2 loads in flight.
// Wave w owns cols [w*1024, +1024); G tiles recomputed via MFMA (emb 1 MB,
// L2-resident).
// ---------------------------------------------------------------------------
__global__ __launch_bounds__(512, 2)
void k_softmax(const unsigned short* __restrict__ embb, const float* __restrict__ sq,
               float* __restrict__ out)
{
    const int tid  = threadIdx.x;
    const int w    = tid >> 6;
    const int lane = tid & 63;
    const int l16  = lane & 15, lhi = lane >> 4;
    const int row0 = blockIdx.x * 16;

    __shared__ float red_s[8][16];
    __shared__ float srow[16];

    bf16x8 afr[2];
    #pragma unroll
    for (int ks = 0; ks < 2; ++ks)
        afr[ks] = *(const bf16x8*)&embb[(size_t)(row0 + l16) * 64 + ks * 32 + lhi * 8];

    float sqr[4];
    #pragma unroll
    for (int i = 0; i < 4; ++i)
        sqr[i] = sq[row0 + lhi * 4 + i];

    const int colw0 = w * 1024;

    auto ldc = [&](int cc, bf16x8& b0, bf16x8& b1, float& sc) {
        int col = colw0 + cc * 16 + l16;
        b0 = *(const bf16x8*)&embb[(size_t)col * 64 + lhi * 8];
        b1 = *(const bf16x8*)&embb[(size_t)col * 64 + 32 + lhi * 8];
        sc = sq[col];
    };

    // ---- pass A: row sum of exp(-d) over this wave's 1024 cols ----
    float s_[4] = {0.f, 0.f, 0.f, 0.f};

    auto procA = [&](bf16x8 b0, bf16x8 b1, float sqc) {
        f32x4 g = {0.f, 0.f, 0.f, 0.f};
        g = MFMA16(afr[0], b0, g);
        g = MFMA16(afr[1], b1, g);
        #pragma unroll
        for (int i = 0; i < 4; ++i) {
            float nd = fminf(__builtin_fmaf(2.0f, g[i], -(sqr[i] + sqc)), 0.0f);
            s_[i] += __expf(nd);
        }
    };

    {
        bf16x8 b0a, b1a, b0b, b1b; float sca, scb;
        ldc(0, b0a, b1a, sca);
        for (int cc = 0; cc < 64; cc += 2) {
            ldc(cc + 1, b0b, b1b, scb);
            procA(b0a, b1a, sca);
            if (cc + 2 < 64) ldc(cc + 2, b0a, b1a, sca);
            procA(b0b, b1b, scb);
        }
    }

    // sum-reduce over the 16 column-lanes (l16)
    #pragma unroll
    for (int off = 1; off < 16; off <<= 1) {
        #pragma unroll
        for (int i = 0; i < 4; ++i)
            s_[i] += __shfl_xor(s_[i], off);
    }
    if (l16 == 0) {
        #pragma unroll
        for (int i = 0; i < 4; ++i)
            red_s[w][lhi * 4 + i] = s_[i];
    }
    __syncthreads();
    if (tid < 16) {
        float s = red_s[0][tid];
        #pragma unroll
        for (int j = 1; j < 8; ++j) s += red_s[j][tid];
        srow[tid] = 1.0f / s;   // s >= exp(-dist_ii) ~= 1 — safe
    }
    __syncthreads();
    float rsloc[4];
    #pragma unroll
    for (int i = 0; i < 4; ++i)
        rsloc[i] = srow[lhi * 4 + i];

    // ---- pass B: recompute, normalize, write (nontemporal streams) ----
    auto procB = [&](int cc, bf16x8 b0, bf16x8 b1, float sqc) {
        f32x4 g = {0.f, 0.f, 0.f, 0.f};
        g = MFMA16(afr[0], b0, g);
        g = MFMA16(afr[1], b1, g);
        int col = colw0 + cc * 16 + l16;
        #pragma unroll
        for (int i = 0; i < 4; ++i) {
            float nd = fminf(__builtin_fmaf(2.0f, g[i], -(sqr[i] + sqc)), 0.0f);
            float p = __expf(nd) * rsloc[i] + 1e-10f;
            int row = row0 + lhi * 4 + i;
            __builtin_nontemporal_store(p, &out[(size_t)row * N_ + col]);
        }
    };

    {
        bf16x8 b0a, b1a, b0b, b1b; float sca, scb;
        ldc(0, b0a, b1a, sca);
        for (int cc = 0; cc < 64; cc += 2) {
            ldc(cc + 1, b0b, b1b, scb);
            procB(cc, b0a, b1a, sca);
            if (cc + 2 < 64) ldc(cc + 2, b0a, b1a, sca);
            procB(cc + 1, b0b, b1b, scb);
        }
    }
}

// ---------------------------------------------------------------------------
// Workspace layout (needs ~12 MB):
//  [0,4M)    AT  bf16 [256][8192]   (X@W1)^T
//  [4M,8M)   h   bf16 [8192][256]
//  [8M,9M)   PT  bf16 [64][8192]    (h@W2)^T
//  [9M,10M)  EB  bf16 [8192][64]    emb
//  [10M,..)  SQ  f32  [8192]
//  [11M,..)  W1T bf16 [256][1024]
//  [11M+512K,..) W2T bf16 [64][256]
// ---------------------------------------------------------------------------
extern "C" void kernel_launch(void* const* d_in, const int* in_sizes, int n_in,
                              void* d_out, int out_size, void* d_ws, size_t ws_size,
                              hipStream_t stream)
{
    const float* L  = (const float*)d_in[0];
    const float* X  = (const float*)d_in[1];
    const float* W1 = (const float*)d_in[2];
    const float* W2 = (const float*)d_in[3];
    float* out = (float*)d_out;
    char* ws = (char*)d_ws;

    unsigned short* AT  = (unsigned short*)(ws);
    unsigned short* Hh  = (unsigned short*)(ws + (4ll  << 20));
    unsigned short* PT  = (unsigned short*)(ws + (8ll  << 20));
    unsigned short* EB  = (unsigned short*)(ws + (9ll  << 20));
    float*          SQ  = (float*)         (ws + (10ll << 20));
    unsigned short* W1T = (unsigned short*)(ws + (11ll << 20));
    unsigned short* W2T = (unsigned short*)(ws + (11ll << 20) + (512ll << 10));

    k_setup<<<(DIN * DMID + DMID * DEMB + 255) / 256, 256, 0, stream>>>(W1, W2, W1T, W2T);

    // A^T = (X @ W1)^T           [256][8192]
    k_gemm<256, 1, 0, 0><<<256, 512, 0, stream>>>(X,  W1T, AT, nullptr, DIN,  DIN,  DIN);
    // h = relu(L @ A)            [8192][256]
    k_gemm<256, 1, 1, 1><<<256, 512, 0, stream>>>(L,  AT,  Hh, nullptr, N_,   N_,   N_);
    // P^T = (h @ W2)^T           [64][8192]
    k_gemm< 64, 0, 0, 0><<<256, 512, 0, stream>>>(Hh, W2T, PT, nullptr, DMID, DMID, DMID);
    // emb = L @ P, sq = rowsum(emb^2)   [8192][64], [8192]
    k_gemm< 64, 1, 2, 0><<<256, 512, 0, stream>>>(L,  PT,  EB, SQ,      N_,   N_,   N_);
    // dist + softmax + 1e-10  -> out [8192][8192]
    k_softmax<<<512, 512, 0, stream>>>(EB, SQ, out);
}